// Round 1
// 1807.438 us; speedup vs baseline: 1.1141x; 1.1141x over previous
//
#include <hip/hip_runtime.h>
#include <hip/hip_bf16.h>
#include <stdint.h>

#define TOK     4096
#define LSEQ    2048
#define DMODEL  2048
#define DINNER  4096
#define DXB     1024
#define DIP     10304
#define NPROJ   10240   /* z + xBC columns; dt columns recomputed in fp32 */
#define CONVDIM 6144
#define DFF     8192
#define NH      64
#define CHUNK   128
#define NCHUNK  16
#define EPSF    1e-5f

typedef __hip_bfloat16 bf16_t;
typedef __bf16 bf16x8 __attribute__((ext_vector_type(8)));
typedef unsigned short u16x8 __attribute__((ext_vector_type(8)));
typedef float f32x4 __attribute__((ext_vector_type(4)));

__device__ __forceinline__ float siluf(float x) { return x / (1.f + __expf(-x)); }
__device__ __forceinline__ float bf2f(bf16_t h) { return __bfloat162float(h); }
__device__ __forceinline__ float bits2f(unsigned short u) { return __uint_as_float((unsigned)u << 16); }
__device__ __forceinline__ unsigned short f2bits(float f) {
  union { bf16_t h; unsigned short u; } cv; cv.h = __float2bfloat16(f); return cv.u;
}
// async global->LDS DMA, 16B per lane; lds dest = wave-uniform base + lane*16
__device__ __forceinline__ void gload_lds16(const void* g, void* l) {
  __builtin_amdgcn_global_load_lds((const __attribute__((address_space(1))) void*)g,
                                   (__attribute__((address_space(3))) void*)l, 16, 0, 0);
}

// ---- transpose fp32 submatrix [R rows][C cols] -> bf16 [C][R] ----
__global__ void k_tcvt(const float* __restrict__ in, bf16_t* __restrict__ out,
                       int R, int C, int rs, int r_off, int c_off) {
  __shared__ float tile[32][33];
  int c0 = blockIdx.x * 32, r0 = blockIdx.y * 32;
  int tx = threadIdx.x, ty = threadIdx.y;  // (32,8)
  for (int i = 0; i < 32; i += 8)
    tile[ty + i][tx] = in[(size_t)(r_off + r0 + ty + i) * rs + c_off + c0 + tx];
  __syncthreads();
  for (int i = 0; i < 32; i += 8)
    out[(size_t)(c0 + ty + i) * R + r0 + tx] = __float2bfloat16(tile[tx][ty + i]);
}

// ---- rmsnorm fp32 -> bf16 ----
__global__ __launch_bounds__(256) void k_rmsnorm_bf16(const float* __restrict__ x,
                                                      const float* __restrict__ w,
                                                      bf16_t* __restrict__ out, int D) {
  int row = blockIdx.x, tid = threadIdx.x;
  const float* xr = x + (size_t)row * D;
  float ss = 0.f;
  for (int j = tid; j < D; j += 256) { float v = xr[j]; ss += v * v; }
  __shared__ float sbuf[4];
  for (int o = 32; o > 0; o >>= 1) ss += __shfl_down(ss, o, 64);
  if ((tid & 63) == 0) sbuf[tid >> 6] = ss;
  __syncthreads();
  float rinv = rsqrtf((sbuf[0] + sbuf[1] + sbuf[2] + sbuf[3]) / D + EPSF);
  bf16_t* orow = out + (size_t)row * D;
  for (int j = tid; j < D; j += 256) orow[j] = __float2bfloat16(xr[j] * rinv * w[j]);
}

// ---- bf16 MFMA GEMM: acc[M][N] = A[M][K] @ Bt[N][K]^T, epilogue by mode ----
// m97-style: global_load_lds width-16 staging, 2-barrier K-loop.
// mode 0: fp32 outp = acc + (auxf ? auxf : 0)            (auxf may alias outp)
// mode 1: bf16 outp = silu(acc)
// mode 2: bf16 outp = acc * (float)outp[idx]   (in-place multiply)
// mode 3: split: n<DINNER -> bf16 outp (ld DINNER); else bf16 out2 (ld CONVDIM)
// Requires M%128==0, N%128==0, K%32==0 (true for all call sites).
__global__ __launch_bounds__(256) void k_gemm(const bf16_t* __restrict__ A,
                                              const bf16_t* __restrict__ Bt,
                                              const float* auxf,
                                              void* outp, void* out2,
                                              int M, int N, int K, int mode) {
  __shared__ unsigned short As[128][32];
  __shared__ unsigned short Bs[128][32];
  const int tid = threadIdx.x;
  const int n0 = blockIdx.x * 128, m0 = blockIdx.y * 128;
  const int lane = tid & 63, w = tid >> 6;
  const int wm = (w >> 1) * 64, wn = (w & 1) * 64;
  const int l16 = lane & 15, quad = lane >> 4;

  // staging map: wave w covers 32 rows (2 DMA calls x 16 rows); lane -> (row, k-half)
  const int srow = lane >> 2;          // 0..15
  const int scol = (lane & 3) * 8;     // bf16 element offset (16B)
  const unsigned short* Ag = (const unsigned short*)A + (size_t)(m0 + w * 32 + srow) * K + scol;
  const unsigned short* Bg = (const unsigned short*)Bt + (size_t)(n0 + w * 32 + srow) * K + scol;
  const size_t K16 = (size_t)16 * K;
  unsigned short* lA0 = &As[w * 32][0];
  unsigned short* lA1 = &As[w * 32 + 16][0];
  unsigned short* lB0 = &Bs[w * 32][0];
  unsigned short* lB1 = &Bs[w * 32 + 16][0];

  f32x4 acc[4][4] = {};
  for (int k0 = 0; k0 < K; k0 += 32) {
    __syncthreads();  // prior iter's ds_reads complete before DMA overwrite
    gload_lds16(Ag, lA0); gload_lds16(Ag + K16, lA1);
    gload_lds16(Bg, lB0); gload_lds16(Bg + K16, lB1);
    Ag += 32; Bg += 32;
    __syncthreads();  // drains vmcnt: DMA landed
    bf16x8 af[4], bfv[4];
#pragma unroll
    for (int mi = 0; mi < 4; mi++) af[mi] = *(const bf16x8*)&As[wm + mi * 16 + l16][quad * 8];
#pragma unroll
    for (int ni = 0; ni < 4; ni++) bfv[ni] = *(const bf16x8*)&Bs[wn + ni * 16 + l16][quad * 8];
#pragma unroll
    for (int mi = 0; mi < 4; mi++)
#pragma unroll
      for (int ni = 0; ni < 4; ni++)
        acc[mi][ni] = __builtin_amdgcn_mfma_f32_16x16x32_bf16(af[mi], bfv[ni], acc[mi][ni], 0, 0, 0);
  }
#pragma unroll
  for (int mi = 0; mi < 4; mi++) {
    const int gm = m0 + wm + mi * 16 + quad * 4;
#pragma unroll
    for (int ni = 0; ni < 4; ni++) {
      const int gn = n0 + wn + ni * 16 + l16;
#pragma unroll
      for (int r = 0; r < 4; r++) {
        const size_t idx = (size_t)(gm + r) * N + gn;
        float v = acc[mi][ni][r];
        if (mode == 0) {
          ((float*)outp)[idx] = v + (auxf ? auxf[idx] : 0.f);
        } else if (mode == 1) {
          ((bf16_t*)outp)[idx] = __float2bfloat16(siluf(v));
        } else if (mode == 2) {
          bf16_t* o = (bf16_t*)outp;
          o[idx] = __float2bfloat16(v * bf2f(o[idx]));
        } else {
          if (gn < DINNER)
            ((bf16_t*)outp)[(size_t)(gm + r) * DINNER + gn] = __float2bfloat16(v);
          else
            ((bf16_t*)out2)[(size_t)(gm + r) * CONVDIM + (gn - DINNER)] = __float2bfloat16(v);
        }
      }
    }
  }
}

// ---- causal depthwise conv(k=4) + silu, bf16 in [TOK][CONVDIM] -> bf16 out ----
__global__ __launch_bounds__(256) void k_conv(const bf16_t* __restrict__ xr,
                                              const float* __restrict__ cw,
                                              const float* __restrict__ cb,
                                              bf16_t* __restrict__ xBC) {
  const int row = blockIdx.x;
  const int t = row & (LSEQ - 1);
  const float4* wv = (const float4*)cw;
  const float4* bv = (const float4*)cb;
  for (int c4 = threadIdx.x; c4 < CONVDIM / 4; c4 += 256) {
    const int c = c4 * 4;
    float4 w0 = wv[c], w1 = wv[c + 1], w2 = wv[c + 2], w3 = wv[c + 3];
    float4 bb = bv[c4];
    const bf16_t* base = xr + (size_t)row * CONVDIM + c;
    ushort4 u0 = *(const ushort4*)base;
    ushort4 u1 = {0,0,0,0}, u2 = {0,0,0,0}, u3 = {0,0,0,0};
    if (t >= 1) u1 = *(const ushort4*)(base - CONVDIM);
    if (t >= 2) u2 = *(const ushort4*)(base - 2 * CONVDIM);
    if (t >= 3) u3 = *(const ushort4*)(base - 3 * CONVDIM);
    ushort4 o;
    o.x = f2bits(siluf(bb.x + w0.x*bits2f(u3.x) + w0.y*bits2f(u2.x) + w0.z*bits2f(u1.x) + w0.w*bits2f(u0.x)));
    o.y = f2bits(siluf(bb.y + w1.x*bits2f(u3.y) + w1.y*bits2f(u2.y) + w1.z*bits2f(u1.y) + w1.w*bits2f(u0.y)));
    o.z = f2bits(siluf(bb.z + w2.x*bits2f(u3.z) + w2.y*bits2f(u2.z) + w2.z*bits2f(u1.z) + w2.w*bits2f(u0.z)));
    o.w = f2bits(siluf(bb.w + w3.x*bits2f(u3.w) + w3.y*bits2f(u2.w) + w3.z*bits2f(u1.w) + w3.w*bits2f(u0.w)));
    *(ushort4*)&xBC[(size_t)row * CONVDIM + c] = o;
  }
}

// ---- fp32 dt: recompute dt columns of in_proj in full precision ----
__global__ __launch_bounds__(256) void k_dt(const float* __restrict__ hs,
                                            const float* __restrict__ ln1,
                                            const float* __restrict__ Wip,
                                            const float* __restrict__ dt_bias,
                                            float* __restrict__ dt) {
  const int row = blockIdx.x, tid = threadIdx.x;
  __shared__ float xs[DMODEL];
  __shared__ float red[4][64];
  __shared__ float sbuf[4];
  const float* xr = hs + (size_t)row * DMODEL;
  float ss = 0.f;
  for (int j = tid; j < DMODEL; j += 256) { float v = xr[j]; ss += v * v; }
  for (int o = 32; o > 0; o >>= 1) ss += __shfl_down(ss, o, 64);
  if ((tid & 63) == 0) sbuf[tid >> 6] = ss;
  __syncthreads();
  float rinv = rsqrtf((sbuf[0] + sbuf[1] + sbuf[2] + sbuf[3]) / DMODEL + EPSF);
  for (int j = tid; j < DMODEL; j += 256) xs[j] = xr[j] * rinv * ln1[j];
  __syncthreads();
  const int h = tid & 63, kq = tid >> 6;
  float acc = 0.f;
  for (int k = kq * 512; k < (kq + 1) * 512; k++)
    acc += xs[k] * Wip[(size_t)k * DIP + 2 * DINNER + 2 * DXB + h];
  red[kq][h] = acc;
  __syncthreads();
  if (tid < 64) {
    float v = red[0][tid] + red[1][tid] + red[2][tid] + red[3][tid] + dt_bias[tid];
    float sp = (v > 20.f) ? v : log1pf(__expf(v));
    dt[(size_t)row * NH + tid] = sp;
  }
}

// ---- per-chunk cumsum of dt*A ----
__global__ void k_dacum(const float* __restrict__ dt, const float* __restrict__ A_log,
                        float* __restrict__ dAc, float* __restrict__ cdec) {
  const int bh = blockIdx.x;  // b*64+h
  const int b = bh >> 6, h = bh & 63;
  const int q = threadIdx.x;  // 128
  const float Ah = -__expf(A_log[h]);
  __shared__ float s[CHUNK];
  for (int c = 0; c < NCHUNK; c++) {
    int row = b * LSEQ + c * CHUNK + q;
    float v = dt[(size_t)row * NH + h] * Ah;
    s[q] = v;
    __syncthreads();
    for (int off = 1; off < CHUNK; off <<= 1) {
      float tadd = (q >= off) ? s[q - off] : 0.f;
      __syncthreads();
      s[q] += tadd;
      __syncthreads();
    }
    float r = s[q];
    dAc[((size_t)bh * NCHUNK + c) * CHUNK + q] = r;
    if (q == CHUNK - 1) cdec[bh * NCHUNK + c] = __expf(r);
    __syncthreads();
  }
}

// ---- per-chunk final states[n][p] (bf16 xBC) ----
__global__ __launch_bounds__(256) void k_states(const bf16_t* __restrict__ xBC,
                                                const float* __restrict__ dtp,
                                                const float* __restrict__ dAc,
                                                float* __restrict__ states) {
  const int blk = blockIdx.x;  // ((b*16+c)*64+h)
  const int h = blk & 63, c = (blk >> 6) & 15, b = blk >> 10;
  const int tid = threadIdx.x;
  const int n0 = (tid >> 4) * 4, p0 = (tid & 15) * 4;
  const int rowb = b * LSEQ + c * CHUNK;
  const int boff = DXB + (h >> 2) * 64, xoff = (h >> 2) * 64;
  __shared__ float Bq[64][64];
  __shared__ float xq[64][64];
  __shared__ float dac_s[CHUNK];
  if (tid < CHUNK) dac_s[tid] = dAc[((size_t)(b * 64 + h) * NCHUNK + c) * CHUNK + tid];
  __syncthreads();
  const float last = dac_s[CHUNK - 1];
  f32x4 acc[4] = {};
  for (int half = 0; half < 2; half++) {
    __syncthreads();
    for (int idx = tid; idx < 64 * 64; idx += 256) {
      int q = idx >> 6, col = idx & 63;
      int row = rowb + half * 64 + q;
      float dec = __expf(last - dac_s[half * 64 + q]);
      const bf16_t* src = xBC + (size_t)row * CONVDIM;
      Bq[q][col] = bf2f(src[boff + col]) * dec;
      xq[q][col] = bf2f(src[xoff + col]) * dtp[(size_t)row * NH + h];
    }
    __syncthreads();
    for (int q = 0; q < 64; q++) {
      f32x4 bv = *(const f32x4*)&Bq[q][n0];
      f32x4 xv = *(const f32x4*)&xq[q][p0];
#pragma unroll
      for (int r = 0; r < 4; r++) acc[r] += bv[r] * xv;
    }
  }
  float* sb = states + (size_t)blk * 4096;
#pragma unroll
  for (int r = 0; r < 4; r++) *(f32x4*)&sb[(n0 + r) * 64 + p0] = acc[r];
}

// ---- sequential scan over chunks ----
__global__ __launch_bounds__(256) void k_scan(const float* __restrict__ states,
                                              const float* __restrict__ cdec,
                                              float* __restrict__ prevs) {
  const int gid = blockIdx.x * 256 + threadIdx.x;  // 2*64*4096
  const int e = gid & 4095;
  const int h = (gid >> 12) & 63;
  const int b = gid >> 18;
  float carry = 0.f;
  for (int c = 0; c < NCHUNK; c++) {
    size_t idx = ((size_t)((b * 16 + c) * 64 + h)) * 4096 + e;
    prevs[idx] = carry;
    carry = states[idx] + cdec[(b * 64 + h) * NCHUNK + c] * carry;
  }
}

// ---- MFMA yout: S = C@B^T (mask/decay -> bf16 P), Y = P@xdt + Cs@prev + D*x ----
// Three bf16 MFMA GEMMs per (b,c,h) block, 4 waves, k_gemm fragment convention:
//   GEMM1: M=128(i) N=128(j) K=64(n)   A=C[i][n]      Bt=B[j][n]
//   GEMM3: M=128(i) N=64(p)  K=64(n)   A=Cs[i][n]     Bt=prevT[p][n]
//   GEMM2: M=128(i) N=64(p)  K=128(j)  A=P[i][j]      Bt=XdtT[p][j]
// LDS overlays: CtX = C tile then XdtT; BtP = B tile then P. All strides
// padded +8 bf16 (144B/272B rows -> 2-way bank aliasing, free).
__global__ __launch_bounds__(256) void k_yout(const bf16_t* __restrict__ xBC,
                                              const float* __restrict__ dtp,
                                              const float* __restrict__ dAc,
                                              const float* __restrict__ prevs,
                                              const float* __restrict__ Dp,
                                              bf16_t* __restrict__ y) {
  const int blk = blockIdx.x;
  const int h = blk & 63, c = (blk >> 6) & 15, b = blk >> 10;
  const int tid = threadIdx.x;
  const int lane = tid & 63, w = tid >> 6;
  const int l16 = lane & 15, quad = lane >> 4;
  const int rowb = b * LSEQ + c * CHUNK;
  const int xoff = (h >> 2) * 64, boff = DXB + (h >> 2) * 64, coff = 2 * DXB + h * 64;

  __shared__ __align__(16) unsigned short CtX[128 * 72];   // C[i][72] -> XdtT[p][136] (64 rows)
  __shared__ __align__(16) unsigned short BtP[128 * 136];  // B[j][136 (use 64)] -> P[i][136]
  __shared__ __align__(16) unsigned short pvT[64 * 72];    // prevT[p][n]
  __shared__ float dac_s[CHUNK];
  __shared__ float dt_s[CHUNK];

  if (tid < CHUNK) {
    dac_s[tid] = dAc[((size_t)(b * 64 + h) * NCHUNK + c) * CHUNK + tid];
    dt_s[tid] = dtp[(size_t)(rowb + tid) * NH + h];
  }
  // stage C and B tiles: 128 rows x 64 cols, 16B vector copies
  for (int idx = tid; idx < 1024; idx += 256) {
    const int i = idx >> 3, e0 = (idx & 7) * 8;
    const unsigned short* src = (const unsigned short*)xBC + (size_t)(rowb + i) * CONVDIM;
    *(u16x8*)&CtX[i * 72 + e0] = *(const u16x8*)&src[coff + e0];
    *(u16x8*)&BtP[i * 136 + e0] = *(const u16x8*)&src[boff + e0];
  }
  // stage prev state transposed: prev[n][p] fp32 -> pvT[p][n] bf16
  {
    const float* pvsrc = prevs + (size_t)blk * 4096;
    for (int idx = tid; idx < 1024; idx += 256) {
      const int n = idx >> 4, p0 = (idx & 15) * 4;
      f32x4 v = *(const f32x4*)&pvsrc[n * 64 + p0];
#pragma unroll
      for (int r = 0; r < 4; r++) pvT[(p0 + r) * 72 + n] = f2bits(v[r]);
    }
  }
  __syncthreads();

  // ---- GEMM1: S quadrants (wave w -> i in [wm,wm+64), j in [wn,wn+64)) ----
  const int wm = (w >> 1) * 64, wn = (w & 1) * 64;
  f32x4 acc1[4][4] = {};
  if (wm >= wn) {  // w==1 quadrant (i<64, j>=64) is fully masked -> skip compute
#pragma unroll
    for (int kk = 0; kk < 2; kk++) {
      bf16x8 af[4], bv[4];
#pragma unroll
      for (int mi = 0; mi < 4; mi++)
        af[mi] = *(const bf16x8*)&CtX[(wm + mi * 16 + l16) * 72 + kk * 32 + quad * 8];
#pragma unroll
      for (int ni = 0; ni < 4; ni++)
        bv[ni] = *(const bf16x8*)&BtP[(wn + ni * 16 + l16) * 136 + kk * 32 + quad * 8];
#pragma unroll
      for (int mi = 0; mi < 4; mi++)
#pragma unroll
        for (int ni = 0; ni < 4; ni++)
          acc1[mi][ni] = __builtin_amdgcn_mfma_f32_16x16x32_bf16(af[mi], bv[ni], acc1[mi][ni], 0, 0, 0);
    }
  }
  __syncthreads();  // all GEMM1 LDS reads done; B region can be overwritten

  // ---- mask + decay S -> bf16 P (overlays B tile); scale C by exp(dac_i) ----
#pragma unroll
  for (int mi = 0; mi < 4; mi++) {
#pragma unroll
    for (int r = 0; r < 4; r++) {
      const int i = wm + mi * 16 + quad * 4 + r;
      const float di = dac_s[i];
#pragma unroll
      for (int ni = 0; ni < 4; ni++) {
        const int j = wn + ni * 16 + l16;
        const float v = (j <= i) ? __expf(di - dac_s[j]) * acc1[mi][ni][r] : 0.f;
        BtP[i * 136 + j] = f2bits(v);
      }
    }
  }
  for (int idx = tid; idx < 1024; idx += 256) {
    const int i = idx >> 3, e0 = (idx & 7) * 8;
    const float sc = __expf(dac_s[i]);
    u16x8 v = *(u16x8*)&CtX[i * 72 + e0];
#pragma unroll
    for (int r = 0; r < 8; r++) v[r] = f2bits(bits2f(v[r]) * sc);
    *(u16x8*)&CtX[i * 72 + e0] = v;
  }
  __syncthreads();

  // ---- GEMM3: acc2 = Cs @ prevT^T  (wave w -> i in [w*32, w*32+32)) ----
  const int wm2 = w * 32;
  f32x4 acc2[2][4] = {};
#pragma unroll
  for (int kk = 0; kk < 2; kk++) {
    bf16x8 af[2], bv[4];
#pragma unroll
    for (int mi = 0; mi < 2; mi++)
      af[mi] = *(const bf16x8*)&CtX[(wm2 + mi * 16 + l16) * 72 + kk * 32 + quad * 8];
#pragma unroll
    for (int ni = 0; ni < 4; ni++)
      bv[ni] = *(const bf16x8*)&pvT[(ni * 16 + l16) * 72 + kk * 32 + quad * 8];
#pragma unroll
    for (int mi = 0; mi < 2; mi++)
#pragma unroll
      for (int ni = 0; ni < 4; ni++)
        acc2[mi][ni] = __builtin_amdgcn_mfma_f32_16x16x32_bf16(af[mi], bv[ni], acc2[mi][ni], 0, 0, 0);
  }
  __syncthreads();  // Cs reads done; C region can be overwritten by XdtT

  // ---- stage xdt transposed: XdtT[p][j] = x[j][p] * dt[j] (overlays C tile) ----
  for (int idx = tid; idx < 1024; idx += 256) {
    const int j = idx >> 3, p0 = (idx & 7) * 8;
    u16x8 v = *(const u16x8*)((const unsigned short*)xBC + (size_t)(rowb + j) * CONVDIM + xoff + p0);
    const float dtj = dt_s[j];
#pragma unroll
    for (int r = 0; r < 8; r++) CtX[(p0 + r) * 136 + j] = f2bits(bits2f(v[r]) * dtj);
  }
  __syncthreads();

  // ---- GEMM2: acc2 += P @ XdtT^T ----
#pragma unroll
  for (int kk = 0; kk < 4; kk++) {
    bf16x8 af[2], bv[4];
#pragma unroll
    for (int mi = 0; mi < 2; mi++)
      af[mi] = *(const bf16x8*)&BtP[(wm2 + mi * 16 + l16) * 136 + kk * 32 + quad * 8];
#pragma unroll
    for (int ni = 0; ni < 4; ni++)
      bv[ni] = *(const bf16x8*)&CtX[(ni * 16 + l16) * 136 + kk * 32 + quad * 8];
#pragma unroll
    for (int mi = 0; mi < 2; mi++)
#pragma unroll
      for (int ni = 0; ni < 4; ni++)
        acc2[mi][ni] = __builtin_amdgcn_mfma_f32_16x16x32_bf16(af[mi], bv[ni], acc2[mi][ni], 0, 0, 0);
  }

  // ---- D*x term in fp32 (D/dt can be ~1e3; keep out of bf16 P) + store ----
  const float Dh = Dp[h];
#pragma unroll
  for (int mi = 0; mi < 2; mi++) {
#pragma unroll
    for (int r = 0; r < 4; r++) {
      const int i = wm2 + mi * 16 + quad * 4 + r;
      const float df = Dh / dt_s[i];
      bf16_t* orow = y + (size_t)(rowb + i) * DINNER + h * 64;
#pragma unroll
      for (int ni = 0; ni < 4; ni++) {
        const int p = ni * 16 + l16;
        const float v = acc2[mi][ni][r] + df * bits2f(CtX[p * 136 + i]);
        orow[p] = __float2bfloat16(v);
      }
    }
  }
}

// ---- gated rmsnorm: yn = rmsnorm(y*silu(z))*w, bf16 in/out ----
__global__ __launch_bounds__(256) void k_gatenorm(const bf16_t* __restrict__ y,
                                                  const bf16_t* __restrict__ z,
                                                  const float* __restrict__ nw,
                                                  bf16_t* __restrict__ outp) {
  const int row = blockIdx.x, tid = threadIdx.x;
  const bf16_t* yr = y + (size_t)row * DINNER;
  const bf16_t* zr = z + (size_t)row * DINNER;
  float vals[16];
  float ss = 0.f;
#pragma unroll
  for (int k = 0; k < 16; k++) {
    int j = tid + k * 256;
    float v = bf2f(yr[j]) * siluf(bf2f(zr[j]));
    vals[k] = v; ss += v * v;
  }
  __shared__ float sbuf[4];
  for (int o = 32; o > 0; o >>= 1) ss += __shfl_down(ss, o, 64);
  if ((tid & 63) == 0) sbuf[tid >> 6] = ss;
  __syncthreads();
  float rinv = rsqrtf((sbuf[0] + sbuf[1] + sbuf[2] + sbuf[3]) / DINNER + EPSF);
  bf16_t* orow = outp + (size_t)row * DINNER;
#pragma unroll
  for (int k = 0; k < 16; k++) {
    int j = tid + k * 256;
    orow[j] = __float2bfloat16(vals[k] * rinv * nw[j]);
  }
}

__global__ void k_diag(float* out, float mb) { out[0] = mb; }

// ---- workspace layout (bytes), total ~245 MB ----
static constexpr size_t OFF_WBUF = 0;                                   // bf16 shared weight buf
static constexpr size_t SZ_WBUF  = (size_t)NPROJ * DMODEL * 2;
static constexpr size_t OFF_Z    = OFF_WBUF + SZ_WBUF;                  // bf16 [TOK][DINNER]
static constexpr size_t SZ_Z     = (size_t)TOK * DINNER * 2;
static constexpr size_t OFF_XBC  = OFF_Z + SZ_Z;                        // bf16 [TOK][CONVDIM]; later hbuf fp32
static constexpr size_t SZ_XBC   = (size_t)TOK * CONVDIM * 2;
static constexpr size_t OFF_DT   = OFF_XBC + SZ_XBC;
static constexpr size_t SZ_DT    = (size_t)TOK * NH * 4;
static constexpr size_t OFF_DAC  = OFF_DT + SZ_DT;
static constexpr size_t SZ_DAC   = (size_t)TOK * NH * 4;
static constexpr size_t OFF_CDEC = OFF_DAC + SZ_DAC;
static constexpr size_t SZ_CDEC  = (size_t)2 * 64 * NCHUNK * 4;
static constexpr size_t OFF_G    = OFF_CDEC + ((SZ_CDEC + 4095) & ~(size_t)4095);  // prevs; later h2n
static constexpr size_t SZ_G     = (size_t)2 * NCHUNK * 64 * 4096 * 4;
static constexpr size_t OFF_H    = OFF_G + SZ_G;                        // xBCraw; later yn; later act
static constexpr size_t SZ_H     = (size_t)TOK * CONVDIM * 2;
static constexpr size_t OFF_I    = OFF_H + SZ_H;                        // xn1; later states; later y
static constexpr size_t SZ_I     = (size_t)2 * NCHUNK * 64 * 4096 * 4;
static constexpr size_t WS_NEED  = OFF_I + SZ_I;

extern "C" void kernel_launch(void* const* d_in, const int* in_sizes, int n_in,
                              void* d_out, int out_size, void* d_ws, size_t ws_size,
                              hipStream_t stream) {
  (void)in_sizes; (void)n_in; (void)out_size;
  if (ws_size < WS_NEED) {
    k_diag<<<1, 1, 0, stream>>>((float*)d_out, (float)(ws_size / 1048576.0));
    return;
  }

  const float* hidden     = (const float*)d_in[0];
  const float* in_proj_w  = (const float*)d_in[1];
  const float* conv_w     = (const float*)d_in[2];
  const float* conv_b     = (const float*)d_in[3];
  const float* dt_bias    = (const float*)d_in[4];
  const float* A_log      = (const float*)d_in[5];
  const float* Dv         = (const float*)d_in[6];
  const float* norm_w     = (const float*)d_in[7];
  const float* out_proj_w = (const float*)d_in[8];
  const float* ln1_w      = (const float*)d_in[9];
  const float* ln2_w      = (const float*)d_in[10];
  const float* gate_w     = (const float*)d_in[11];
  const float* up_w       = (const float*)d_in[12];
  const float* down_w     = (const float*)d_in[13];

  char* ws = (char*)d_ws;
  bf16_t* Wbuf  = (bf16_t*)(ws + OFF_WBUF);
  bf16_t* z     = (bf16_t*)(ws + OFF_Z);
  bf16_t* xBC   = (bf16_t*)(ws + OFF_XBC);
  float*  hbuf  = (float*)(ws + OFF_XBC);   // overlay (xBC dead after yout)
  float*  dtb   = (float*)(ws + OFF_DT);
  float*  dAc   = (float*)(ws + OFF_DAC);
  float*  cdec  = (float*)(ws + OFF_CDEC);
  float*  prevs = (float*)(ws + OFF_G);
  bf16_t* h2n   = (bf16_t*)(ws + OFF_G);    // overlay (prevs dead after yout)
  bf16_t* xbcr  = (bf16_t*)(ws + OFF_H);
  bf16_t* yn    = (bf16_t*)(ws + OFF_H);    // overlay (xbcr dead after conv)
  bf16_t* act   = (bf16_t*)(ws + OFF_H);    // overlay (yn dead after out_proj)
  bf16_t* xn1   = (bf16_t*)(ws + OFF_I);
  float*  states= (float*)(ws + OFF_I);     // overlay (xn1 dead after in_proj)
  bf16_t* y     = (bf16_t*)(ws + OFF_I);    // overlay (states dead after scan)

  dim3 tb(32, 8);

  // ---- mamba block ----
  k_tcvt<<<dim3(NPROJ / 32, DMODEL / 32), tb, 0, stream>>>(in_proj_w, Wbuf, DMODEL, NPROJ, DIP, 0, 0);
  k_rmsnorm_bf16<<<TOK, 256, 0, stream>>>(hidden, ln1_w, xn1, DMODEL);
  k_gemm<<<dim3(NPROJ / 128, TOK / 128), 256, 0, stream>>>(xn1, Wbuf, nullptr, z, xbcr, TOK, NPROJ, DMODEL, 3);
  k_conv<<<TOK, 256, 0, stream>>>(xbcr, conv_w, conv_b, xBC);
  k_dt<<<TOK, 256, 0, stream>>>(hidden, ln1_w, in_proj_w, dt_bias, dtb);
  k_dacum<<<128, 128, 0, stream>>>(dtb, A_log, dAc, cdec);
  k_states<<<2048, 256, 0, stream>>>(xBC, dtb, dAc, states);
  k_scan<<<2048, 256, 0, stream>>>(states, cdec, prevs);
  k_yout<<<2048, 256, 0, stream>>>(xBC, dtb, dAc, prevs, Dv, y);
  k_gatenorm<<<TOK, 256, 0, stream>>>(y, z, norm_w, yn);
  k_tcvt<<<dim3(DMODEL / 32, DINNER / 32), tb, 0, stream>>>(out_proj_w, Wbuf, DINNER, DMODEL, DMODEL, 0, 0);
  k_gemm<<<dim3(DMODEL / 128, TOK / 128), 256, 0, stream>>>(yn, Wbuf, hidden, hbuf, nullptr, TOK, DMODEL, DINNER, 0);

  // ---- MLP block (two N-halves to bound scratch) ----
  k_rmsnorm_bf16<<<TOK, 256, 0, stream>>>(hbuf, ln2_w, h2n, DMODEL);
  for (int g = 0; g < 2; g++) {
    const int HF = DFF / 2;  // 4096
    k_tcvt<<<dim3(HF / 32, DMODEL / 32), tb, 0, stream>>>(gate_w, Wbuf, DMODEL, HF, DFF, 0, g * HF);
    k_gemm<<<dim3(HF / 128, TOK / 128), 256, 0, stream>>>(h2n, Wbuf, nullptr, act, nullptr, TOK, HF, DMODEL, 1);
    k_tcvt<<<dim3(HF / 32, DMODEL / 32), tb, 0, stream>>>(up_w, Wbuf, DMODEL, HF, DFF, 0, g * HF);
    k_gemm<<<dim3(HF / 128, TOK / 128), 256, 0, stream>>>(h2n, Wbuf, nullptr, act, nullptr, TOK, HF, DMODEL, 2);
    k_tcvt<<<dim3(DMODEL / 32, HF / 32), tb, 0, stream>>>(down_w, Wbuf, HF, DMODEL, DMODEL, g * HF, 0);
    k_gemm<<<dim3(DMODEL / 128, TOK / 128), 256, 0, stream>>>(act, Wbuf, g == 0 ? hbuf : (float*)d_out,
                                                              d_out, nullptr, TOK, DMODEL, HF, 0);
  }
}

// Round 2
// 1618.785 us; speedup vs baseline: 1.2439x; 1.1165x over previous
//
#include <hip/hip_runtime.h>
#include <hip/hip_bf16.h>
#include <stdint.h>

#define TOK     4096
#define LSEQ    2048
#define DMODEL  2048
#define DINNER  4096
#define DXB     1024
#define DIP     10304
#define NPROJ   10240   /* z + xBC columns; dt columns recomputed in fp32 */
#define CONVDIM 6144
#define DFF     8192
#define NH      64
#define CHUNK   128
#define NCHUNK  16
#define EPSF    1e-5f

typedef __hip_bfloat16 bf16_t;
typedef __bf16 bf16x8 __attribute__((ext_vector_type(8)));
typedef unsigned short u16x8 __attribute__((ext_vector_type(8)));
typedef float f32x4 __attribute__((ext_vector_type(4)));

__device__ __forceinline__ float siluf(float x) { return x / (1.f + __expf(-x)); }
__device__ __forceinline__ float bf2f(bf16_t h) { return __bfloat162float(h); }
__device__ __forceinline__ float bits2f(unsigned short u) { return __uint_as_float((unsigned)u << 16); }
__device__ __forceinline__ unsigned short f2bits(float f) {
  union { bf16_t h; unsigned short u; } cv; cv.h = __float2bfloat16(f); return cv.u;
}
// async global->LDS DMA, 16B per lane; lds dest = wave-uniform base + lane*16
__device__ __forceinline__ void gload_lds16(const void* g, void* l) {
  __builtin_amdgcn_global_load_lds((const __attribute__((address_space(1))) void*)g,
                                   (__attribute__((address_space(3))) void*)l, 16, 0, 0);
}

// ---- transpose fp32 submatrix [R rows][C cols] -> bf16 [C][R] ----
__global__ void k_tcvt(const float* __restrict__ in, bf16_t* __restrict__ out,
                       int R, int C, int rs, int r_off, int c_off) {
  __shared__ float tile[32][33];
  int c0 = blockIdx.x * 32, r0 = blockIdx.y * 32;
  int tx = threadIdx.x, ty = threadIdx.y;  // (32,8)
  for (int i = 0; i < 32; i += 8)
    tile[ty + i][tx] = in[(size_t)(r_off + r0 + ty + i) * rs + c_off + c0 + tx];
  __syncthreads();
  for (int i = 0; i < 32; i += 8)
    out[(size_t)(c0 + ty + i) * R + r0 + tx] = __float2bfloat16(tile[tx][ty + i]);
}

// ---- rmsnorm fp32 -> bf16 ----
__global__ __launch_bounds__(256) void k_rmsnorm_bf16(const float* __restrict__ x,
                                                      const float* __restrict__ w,
                                                      bf16_t* __restrict__ out, int D) {
  int row = blockIdx.x, tid = threadIdx.x;
  const float* xr = x + (size_t)row * D;
  float ss = 0.f;
  for (int j = tid; j < D; j += 256) { float v = xr[j]; ss += v * v; }
  __shared__ float sbuf[4];
  for (int o = 32; o > 0; o >>= 1) ss += __shfl_down(ss, o, 64);
  if ((tid & 63) == 0) sbuf[tid >> 6] = ss;
  __syncthreads();
  float rinv = rsqrtf((sbuf[0] + sbuf[1] + sbuf[2] + sbuf[3]) / D + EPSF);
  bf16_t* orow = out + (size_t)row * D;
  for (int j = tid; j < D; j += 256) orow[j] = __float2bfloat16(xr[j] * rinv * w[j]);
}

// ---- bf16 MFMA GEMM (128x128 tile, m97-style) for N=2048 call sites ----
// mode 0: fp32 outp = acc + (auxf ? auxf : 0)            (auxf may alias outp)
// mode 1: bf16 outp = silu(acc)
// mode 2: bf16 outp = acc * (float)outp[idx]   (in-place multiply)
// mode 3: split: n<DINNER -> bf16 outp (ld DINNER); else bf16 out2 (ld CONVDIM)
__global__ __launch_bounds__(256) void k_gemm(const bf16_t* __restrict__ A,
                                              const bf16_t* __restrict__ Bt,
                                              const float* auxf,
                                              void* outp, void* out2,
                                              int M, int N, int K, int mode) {
  __shared__ unsigned short As[128][32];
  __shared__ unsigned short Bs[128][32];
  const int tid = threadIdx.x;
  const int n0 = blockIdx.x * 128, m0 = blockIdx.y * 128;
  const int lane = tid & 63, w = tid >> 6;
  const int wm = (w >> 1) * 64, wn = (w & 1) * 64;
  const int l16 = lane & 15, quad = lane >> 4;

  const int srow = lane >> 2;          // 0..15
  const int scol = (lane & 3) * 8;     // bf16 element offset (16B)
  const unsigned short* Ag = (const unsigned short*)A + (size_t)(m0 + w * 32 + srow) * K + scol;
  const unsigned short* Bg = (const unsigned short*)Bt + (size_t)(n0 + w * 32 + srow) * K + scol;
  const size_t K16 = (size_t)16 * K;
  unsigned short* lA0 = &As[w * 32][0];
  unsigned short* lA1 = &As[w * 32 + 16][0];
  unsigned short* lB0 = &Bs[w * 32][0];
  unsigned short* lB1 = &Bs[w * 32 + 16][0];

  f32x4 acc[4][4] = {};
  for (int k0 = 0; k0 < K; k0 += 32) {
    __syncthreads();  // prior iter's ds_reads complete before DMA overwrite
    gload_lds16(Ag, lA0); gload_lds16(Ag + K16, lA1);
    gload_lds16(Bg, lB0); gload_lds16(Bg + K16, lB1);
    Ag += 32; Bg += 32;
    __syncthreads();  // drains vmcnt: DMA landed
    bf16x8 af[4], bfv[4];
#pragma unroll
    for (int mi = 0; mi < 4; mi++) af[mi] = *(const bf16x8*)&As[wm + mi * 16 + l16][quad * 8];
#pragma unroll
    for (int ni = 0; ni < 4; ni++) bfv[ni] = *(const bf16x8*)&Bs[wn + ni * 16 + l16][quad * 8];
#pragma unroll
    for (int mi = 0; mi < 4; mi++)
#pragma unroll
      for (int ni = 0; ni < 4; ni++)
        acc[mi][ni] = __builtin_amdgcn_mfma_f32_16x16x32_bf16(af[mi], bfv[ni], acc[mi][ni], 0, 0, 0);
  }
#pragma unroll
  for (int mi = 0; mi < 4; mi++) {
    const int gm = m0 + wm + mi * 16 + quad * 4;
#pragma unroll
    for (int ni = 0; ni < 4; ni++) {
      const int gn = n0 + wn + ni * 16 + l16;
#pragma unroll
      for (int r = 0; r < 4; r++) {
        const size_t idx = (size_t)(gm + r) * N + gn;
        float v = acc[mi][ni][r];
        if (mode == 0) {
          ((float*)outp)[idx] = v + (auxf ? auxf[idx] : 0.f);
        } else if (mode == 1) {
          ((bf16_t*)outp)[idx] = __float2bfloat16(siluf(v));
        } else if (mode == 2) {
          bf16_t* o = (bf16_t*)outp;
          o[idx] = __float2bfloat16(v * bf2f(o[idx]));
        } else {
          if (gn < DINNER)
            ((bf16_t*)outp)[(size_t)(gm + r) * DINNER + gn] = __float2bfloat16(v);
          else
            ((bf16_t*)out2)[(size_t)(gm + r) * CONVDIM + (gn - DINNER)] = __float2bfloat16(v);
        }
      }
    }
  }
}

// ---- 256x256/BK=64 pipelined MFMA GEMM: counted vmcnt + XOR-swizzled LDS ----
// 8 waves (2M x 4N), 128 KiB double-buffered LDS, depth-2 K-tile prefetch.
// Swizzle (rule 21, both-sides): LDS stays LINEAR for global_load_lds; the
// global SOURCE column-slot is pre-swizzled (slot ^ row&7) and ds_reads apply
// the same involution -> b128 reads hit all 8 bank-quads uniformly.
// Race-free staging: tile t+2's DMA into buf[t&1] is issued only after a raw
// s_barrier that follows every wave's lgkmcnt(0) (all reads of tile t done).
// vmcnt(8) = tile t+1's 8 outstanding DMA instructions stay in flight.
__global__ __launch_bounds__(512) void k_gemm256(const bf16_t* __restrict__ A,
                                                 const bf16_t* __restrict__ Bt,
                                                 const float* auxf,
                                                 void* outp, void* out2,
                                                 int M, int N, int K, int mode) {
  __shared__ __align__(16) unsigned short lds[2][2][16384];  // [buf][A/B][256*64]
  const int tid = threadIdx.x;
  const int lane = tid & 63, w = tid >> 6;        // 8 waves
  const int wm = w >> 2, wn = w & 3;              // wave_m {0,1}, wave_n {0..3}
  const int l16 = lane & 15, quad = lane >> 4;
  const int n0 = blockIdx.x * 256, m0 = blockIdx.y * 256;

  // staging: call covers 64 rows x 128B; wave w -> 8 rows; lane -> (row, slot)
  const int srow = lane >> 3;                     // 0..7
  const int sslot = (lane & 7) ^ srow;            // inverse-swizzled source slot
  const unsigned short* Ag = (const unsigned short*)A + (size_t)(m0 + w * 8 + srow) * K + sslot * 8;
  const unsigned short* Bg = (const unsigned short*)Bt + (size_t)(n0 + w * 8 + srow) * K + sslot * 8;
  const size_t rowadv = (size_t)64 * K;

  f32x4 acc[8][4] = {};
  const int NT = K >> 6;

#define STAGE256(buf, coloff)                                            \
  do {                                                                   \
    unsigned short* la_ = &lds[buf][0][w * 512];                         \
    unsigned short* lb_ = &lds[buf][1][w * 512];                         \
    _Pragma("unroll")                                                    \
    for (int c_ = 0; c_ < 4; c_++) {                                     \
      gload_lds16(Ag + (coloff) + c_ * rowadv, la_ + c_ * 4096);         \
      gload_lds16(Bg + (coloff) + c_ * rowadv, lb_ + c_ * 4096);         \
    }                                                                    \
  } while (0)

  STAGE256(0, 0);
  STAGE256(1, 64);

  for (int t = 0; t < NT; t++) {
    const int cur = t & 1;
    if (t < NT - 1) asm volatile("s_waitcnt vmcnt(8)" ::: "memory");
    else            asm volatile("s_waitcnt vmcnt(0)" ::: "memory");
    __builtin_amdgcn_s_barrier();               // buf[cur] fully landed for all waves
    bf16x8 af[2][8], bv[2][4];
    const unsigned short* la = &lds[cur][0][0];
    const unsigned short* lb = &lds[cur][1][0];
#pragma unroll
    for (int kk = 0; kk < 2; kk++) {
#pragma unroll
      for (int f = 0; f < 8; f++) {
        const int row = wm * 128 + f * 16 + l16;
        const int slot = (kk * 4 + quad) ^ (row & 7);
        af[kk][f] = *(const bf16x8*)&la[row * 64 + slot * 8];
      }
#pragma unroll
      for (int n = 0; n < 4; n++) {
        const int row = wn * 64 + n * 16 + l16;
        const int slot = (kk * 4 + quad) ^ (row & 7);
        bv[kk][n] = *(const bf16x8*)&lb[row * 64 + slot * 8];
      }
    }
    asm volatile("s_waitcnt lgkmcnt(0)" ::: "memory");  // this wave's reads in regs
    __builtin_amdgcn_sched_barrier(0);
    __builtin_amdgcn_s_barrier();               // ALL waves done reading buf[cur]
    if (t + 2 < NT) STAGE256(cur, (size_t)(t + 2) * 64);  // safe overwrite, async
    __builtin_amdgcn_s_setprio(1);
#pragma unroll
    for (int kk = 0; kk < 2; kk++)
#pragma unroll
      for (int f = 0; f < 8; f++)
#pragma unroll
        for (int n = 0; n < 4; n++)
          acc[f][n] = __builtin_amdgcn_mfma_f32_16x16x32_bf16(af[kk][f], bv[kk][n], acc[f][n], 0, 0, 0);
    __builtin_amdgcn_s_setprio(0);
  }
#undef STAGE256

#pragma unroll
  for (int f = 0; f < 8; f++) {
    const int gm = m0 + wm * 128 + f * 16 + quad * 4;
#pragma unroll
    for (int n = 0; n < 4; n++) {
      const int gn = n0 + wn * 64 + n * 16 + l16;
#pragma unroll
      for (int r = 0; r < 4; r++) {
        const size_t idx = (size_t)(gm + r) * N + gn;
        float v = acc[f][n][r];
        if (mode == 0) {
          ((float*)outp)[idx] = v + (auxf ? auxf[idx] : 0.f);
        } else if (mode == 1) {
          ((bf16_t*)outp)[idx] = __float2bfloat16(siluf(v));
        } else if (mode == 2) {
          bf16_t* o = (bf16_t*)outp;
          o[idx] = __float2bfloat16(v * bf2f(o[idx]));
        } else {
          if (gn < DINNER)
            ((bf16_t*)outp)[(size_t)(gm + r) * DINNER + gn] = __float2bfloat16(v);
          else
            ((bf16_t*)out2)[(size_t)(gm + r) * CONVDIM + (gn - DINNER)] = __float2bfloat16(v);
        }
      }
    }
  }
}

// ---- causal depthwise conv(k=4) + silu, bf16 in [TOK][CONVDIM] -> bf16 out ----
__global__ __launch_bounds__(256) void k_conv(const bf16_t* __restrict__ xr,
                                              const float* __restrict__ cw,
                                              const float* __restrict__ cb,
                                              bf16_t* __restrict__ xBC) {
  const int row = blockIdx.x;
  const int t = row & (LSEQ - 1);
  const float4* wv = (const float4*)cw;
  const float4* bv = (const float4*)cb;
  for (int c4 = threadIdx.x; c4 < CONVDIM / 4; c4 += 256) {
    const int c = c4 * 4;
    float4 w0 = wv[c], w1 = wv[c + 1], w2 = wv[c + 2], w3 = wv[c + 3];
    float4 bb = bv[c4];
    const bf16_t* base = xr + (size_t)row * CONVDIM + c;
    ushort4 u0 = *(const ushort4*)base;
    ushort4 u1 = {0,0,0,0}, u2 = {0,0,0,0}, u3 = {0,0,0,0};
    if (t >= 1) u1 = *(const ushort4*)(base - CONVDIM);
    if (t >= 2) u2 = *(const ushort4*)(base - 2 * CONVDIM);
    if (t >= 3) u3 = *(const ushort4*)(base - 3 * CONVDIM);
    ushort4 o;
    o.x = f2bits(siluf(bb.x + w0.x*bits2f(u3.x) + w0.y*bits2f(u2.x) + w0.z*bits2f(u1.x) + w0.w*bits2f(u0.x)));
    o.y = f2bits(siluf(bb.y + w1.x*bits2f(u3.y) + w1.y*bits2f(u2.y) + w1.z*bits2f(u1.y) + w1.w*bits2f(u0.y)));
    o.z = f2bits(siluf(bb.z + w2.x*bits2f(u3.z) + w2.y*bits2f(u2.z) + w2.z*bits2f(u1.z) + w2.w*bits2f(u0.z)));
    o.w = f2bits(siluf(bb.w + w3.x*bits2f(u3.w) + w3.y*bits2f(u2.w) + w3.z*bits2f(u1.w) + w3.w*bits2f(u0.w)));
    *(ushort4*)&xBC[(size_t)row * CONVDIM + c] = o;
  }
}

// ---- fp32 dt: recompute dt columns of in_proj in full precision ----
__global__ __launch_bounds__(256) void k_dt(const float* __restrict__ hs,
                                            const float* __restrict__ ln1,
                                            const float* __restrict__ Wip,
                                            const float* __restrict__ dt_bias,
                                            float* __restrict__ dt) {
  const int row = blockIdx.x, tid = threadIdx.x;
  __shared__ float xs[DMODEL];
  __shared__ float red[4][64];
  __shared__ float sbuf[4];
  const float* xr = hs + (size_t)row * DMODEL;
  float ss = 0.f;
  for (int j = tid; j < DMODEL; j += 256) { float v = xr[j]; ss += v * v; }
  for (int o = 32; o > 0; o >>= 1) ss += __shfl_down(ss, o, 64);
  if ((tid & 63) == 0) sbuf[tid >> 6] = ss;
  __syncthreads();
  float rinv = rsqrtf((sbuf[0] + sbuf[1] + sbuf[2] + sbuf[3]) / DMODEL + EPSF);
  for (int j = tid; j < DMODEL; j += 256) xs[j] = xr[j] * rinv * ln1[j];
  __syncthreads();
  const int h = tid & 63, kq = tid >> 6;
  float acc = 0.f;
  for (int k = kq * 512; k < (kq + 1) * 512; k++)
    acc += xs[k] * Wip[(size_t)k * DIP + 2 * DINNER + 2 * DXB + h];
  red[kq][h] = acc;
  __syncthreads();
  if (tid < 64) {
    float v = red[0][tid] + red[1][tid] + red[2][tid] + red[3][tid] + dt_bias[tid];
    float sp = (v > 20.f) ? v : log1pf(__expf(v));
    dt[(size_t)row * NH + tid] = sp;
  }
}

// ---- per-chunk cumsum of dt*A ----
__global__ void k_dacum(const float* __restrict__ dt, const float* __restrict__ A_log,
                        float* __restrict__ dAc, float* __restrict__ cdec) {
  const int bh = blockIdx.x;  // b*64+h
  const int b = bh >> 6, h = bh & 63;
  const int q = threadIdx.x;  // 128
  const float Ah = -__expf(A_log[h]);
  __shared__ float s[CHUNK];
  for (int c = 0; c < NCHUNK; c++) {
    int row = b * LSEQ + c * CHUNK + q;
    float v = dt[(size_t)row * NH + h] * Ah;
    s[q] = v;
    __syncthreads();
    for (int off = 1; off < CHUNK; off <<= 1) {
      float tadd = (q >= off) ? s[q - off] : 0.f;
      __syncthreads();
      s[q] += tadd;
      __syncthreads();
    }
    float r = s[q];
    dAc[((size_t)bh * NCHUNK + c) * CHUNK + q] = r;
    if (q == CHUNK - 1) cdec[bh * NCHUNK + c] = __expf(r);
    __syncthreads();
  }
}

// ---- per-chunk final states[n][p] (bf16 xBC) ----
__global__ __launch_bounds__(256) void k_states(const bf16_t* __restrict__ xBC,
                                                const float* __restrict__ dtp,
                                                const float* __restrict__ dAc,
                                                float* __restrict__ states) {
  const int blk = blockIdx.x;  // ((b*16+c)*64+h)
  const int h = blk & 63, c = (blk >> 6) & 15, b = blk >> 10;
  const int tid = threadIdx.x;
  const int n0 = (tid >> 4) * 4, p0 = (tid & 15) * 4;
  const int rowb = b * LSEQ + c * CHUNK;
  const int boff = DXB + (h >> 2) * 64, xoff = (h >> 2) * 64;
  __shared__ float Bq[64][64];
  __shared__ float xq[64][64];
  __shared__ float dac_s[CHUNK];
  if (tid < CHUNK) dac_s[tid] = dAc[((size_t)(b * 64 + h) * NCHUNK + c) * CHUNK + tid];
  __syncthreads();
  const float last = dac_s[CHUNK - 1];
  f32x4 acc[4] = {};
  for (int half = 0; half < 2; half++) {
    __syncthreads();
    for (int idx = tid; idx < 64 * 64; idx += 256) {
      int q = idx >> 6, col = idx & 63;
      int row = rowb + half * 64 + q;
      float dec = __expf(last - dac_s[half * 64 + q]);
      const bf16_t* src = xBC + (size_t)row * CONVDIM;
      Bq[q][col] = bf2f(src[boff + col]) * dec;
      xq[q][col] = bf2f(src[xoff + col]) * dtp[(size_t)row * NH + h];
    }
    __syncthreads();
    for (int q = 0; q < 64; q++) {
      f32x4 bv = *(const f32x4*)&Bq[q][n0];
      f32x4 xv = *(const f32x4*)&xq[q][p0];
#pragma unroll
      for (int r = 0; r < 4; r++) acc[r] += bv[r] * xv;
    }
  }
  float* sb = states + (size_t)blk * 4096;
#pragma unroll
  for (int r = 0; r < 4; r++) *(f32x4*)&sb[(n0 + r) * 64 + p0] = acc[r];
}

// ---- sequential scan over chunks ----
__global__ __launch_bounds__(256) void k_scan(const float* __restrict__ states,
                                              const float* __restrict__ cdec,
                                              float* __restrict__ prevs) {
  const int gid = blockIdx.x * 256 + threadIdx.x;  // 2*64*4096
  const int e = gid & 4095;
  const int h = (gid >> 12) & 63;
  const int b = gid >> 18;
  float carry = 0.f;
  for (int c = 0; c < NCHUNK; c++) {
    size_t idx = ((size_t)((b * 16 + c) * 64 + h)) * 4096 + e;
    prevs[idx] = carry;
    carry = states[idx] + cdec[(b * 64 + h) * NCHUNK + c] * carry;
  }
}

// ---- MFMA yout: S = C@B^T (mask/decay -> bf16 P), Y = P@xdt + Cs@prev + D*x ----
__global__ __launch_bounds__(256) void k_yout(const bf16_t* __restrict__ xBC,
                                              const float* __restrict__ dtp,
                                              const float* __restrict__ dAc,
                                              const float* __restrict__ prevs,
                                              const float* __restrict__ Dp,
                                              bf16_t* __restrict__ y) {
  const int blk = blockIdx.x;
  const int h = blk & 63, c = (blk >> 6) & 15, b = blk >> 10;
  const int tid = threadIdx.x;
  const int lane = tid & 63, w = tid >> 6;
  const int l16 = lane & 15, quad = lane >> 4;
  const int rowb = b * LSEQ + c * CHUNK;
  const int xoff = (h >> 2) * 64, boff = DXB + (h >> 2) * 64, coff = 2 * DXB + h * 64;

  __shared__ __align__(16) unsigned short CtX[128 * 72];   // C[i][72] -> XdtT[p][136] (64 rows)
  __shared__ __align__(16) unsigned short BtP[128 * 136];  // B[j][136 (use 64)] -> P[i][136]
  __shared__ __align__(16) unsigned short pvT[64 * 72];    // prevT[p][n]
  __shared__ float dac_s[CHUNK];
  __shared__ float dt_s[CHUNK];

  if (tid < CHUNK) {
    dac_s[tid] = dAc[((size_t)(b * 64 + h) * NCHUNK + c) * CHUNK + tid];
    dt_s[tid] = dtp[(size_t)(rowb + tid) * NH + h];
  }
  for (int idx = tid; idx < 1024; idx += 256) {
    const int i = idx >> 3, e0 = (idx & 7) * 8;
    const unsigned short* src = (const unsigned short*)xBC + (size_t)(rowb + i) * CONVDIM;
    *(u16x8*)&CtX[i * 72 + e0] = *(const u16x8*)&src[coff + e0];
    *(u16x8*)&BtP[i * 136 + e0] = *(const u16x8*)&src[boff + e0];
  }
  {
    const float* pvsrc = prevs + (size_t)blk * 4096;
    for (int idx = tid; idx < 1024; idx += 256) {
      const int n = idx >> 4, p0 = (idx & 15) * 4;
      f32x4 v = *(const f32x4*)&pvsrc[n * 64 + p0];
#pragma unroll
      for (int r = 0; r < 4; r++) pvT[(p0 + r) * 72 + n] = f2bits(v[r]);
    }
  }
  __syncthreads();

  // ---- GEMM1: S quadrants (wave w -> i in [wm,wm+64), j in [wn,wn+64)) ----
  const int wm = (w >> 1) * 64, wn = (w & 1) * 64;
  f32x4 acc1[4][4] = {};
  if (wm >= wn) {  // w==1 quadrant (i<64, j>=64) is fully masked -> skip compute
#pragma unroll
    for (int kk = 0; kk < 2; kk++) {
      bf16x8 af[4], bv[4];
#pragma unroll
      for (int mi = 0; mi < 4; mi++)
        af[mi] = *(const bf16x8*)&CtX[(wm + mi * 16 + l16) * 72 + kk * 32 + quad * 8];
#pragma unroll
      for (int ni = 0; ni < 4; ni++)
        bv[ni] = *(const bf16x8*)&BtP[(wn + ni * 16 + l16) * 136 + kk * 32 + quad * 8];
#pragma unroll
      for (int mi = 0; mi < 4; mi++)
#pragma unroll
        for (int ni = 0; ni < 4; ni++)
          acc1[mi][ni] = __builtin_amdgcn_mfma_f32_16x16x32_bf16(af[mi], bv[ni], acc1[mi][ni], 0, 0, 0);
    }
  }
  __syncthreads();  // all GEMM1 LDS reads done; B region can be overwritten

  // ---- mask + decay S -> bf16 P (overlays B tile); scale C by exp(dac_i) ----
#pragma unroll
  for (int mi = 0; mi < 4; mi++) {
#pragma unroll
    for (int r = 0; r < 4; r++) {
      const int i = wm + mi * 16 + quad * 4 + r;
      const float di = dac_s[i];
#pragma unroll
      for (int ni = 0; ni < 4; ni++) {
        const int j = wn + ni * 16 + l16;
        const float v = (j <= i) ? __expf(di - dac_s[j]) * acc1[mi][ni][r] : 0.f;
        BtP[i * 136 + j] = f2bits(v);
      }
    }
  }
  for (int idx = tid; idx < 1024; idx += 256) {
    const int i = idx >> 3, e0 = (idx & 7) * 8;
    const float sc = __expf(dac_s[i]);
    u16x8 v = *(u16x8*)&CtX[i * 72 + e0];
#pragma unroll
    for (int r = 0; r < 8; r++) v[r] = f2bits(bits2f(v[r]) * sc);
    *(u16x8*)&CtX[i * 72 + e0] = v;
  }
  __syncthreads();

  // ---- GEMM3: acc2 = Cs @ prevT^T  (wave w -> i in [w*32, w*32+32)) ----
  const int wm2 = w * 32;
  f32x4 acc2[2][4] = {};
#pragma unroll
  for (int kk = 0; kk < 2; kk++) {
    bf16x8 af[2], bv[4];
#pragma unroll
    for (int mi = 0; mi < 2; mi++)
      af[mi] = *(const bf16x8*)&CtX[(wm2 + mi * 16 + l16) * 72 + kk * 32 + quad * 8];
#pragma unroll
    for (int ni = 0; ni < 4; ni++)
      bv[ni] = *(const bf16x8*)&pvT[(ni * 16 + l16) * 72 + kk * 32 + quad * 8];
#pragma unroll
    for (int mi = 0; mi < 2; mi++)
#pragma unroll
      for (int ni = 0; ni < 4; ni++)
        acc2[mi][ni] = __builtin_amdgcn_mfma_f32_16x16x32_bf16(af[mi], bv[ni], acc2[mi][ni], 0, 0, 0);
  }
  __syncthreads();  // Cs reads done; C region can be overwritten by XdtT

  // ---- stage xdt transposed: XdtT[p][j] = x[j][p] * dt[j] (overlays C tile) ----
  for (int idx = tid; idx < 1024; idx += 256) {
    const int j = idx >> 3, p0 = (idx & 7) * 8;
    u16x8 v = *(const u16x8*)((const unsigned short*)xBC + (size_t)(rowb + j) * CONVDIM + xoff + p0);
    const float dtj = dt_s[j];
#pragma unroll
    for (int r = 0; r < 8; r++) CtX[(p0 + r) * 136 + j] = f2bits(bits2f(v[r]) * dtj);
  }
  __syncthreads();

  // ---- GEMM2: acc2 += P @ XdtT^T ----
#pragma unroll
  for (int kk = 0; kk < 4; kk++) {
    bf16x8 af[2], bv[4];
#pragma unroll
    for (int mi = 0; mi < 2; mi++)
      af[mi] = *(const bf16x8*)&BtP[(wm2 + mi * 16 + l16) * 136 + kk * 32 + quad * 8];
#pragma unroll
    for (int ni = 0; ni < 4; ni++)
      bv[ni] = *(const bf16x8*)&CtX[(ni * 16 + l16) * 136 + kk * 32 + quad * 8];
#pragma unroll
    for (int mi = 0; mi < 2; mi++)
#pragma unroll
      for (int ni = 0; ni < 4; ni++)
        acc2[mi][ni] = __builtin_amdgcn_mfma_f32_16x16x32_bf16(af[mi], bv[ni], acc2[mi][ni], 0, 0, 0);
  }

  // ---- D*x term in fp32 (D/dt can be ~1e3; keep out of bf16 P) + store ----
  const float Dh = Dp[h];
#pragma unroll
  for (int mi = 0; mi < 2; mi++) {
#pragma unroll
    for (int r = 0; r < 4; r++) {
      const int i = wm2 + mi * 16 + quad * 4 + r;
      const float df = Dh / dt_s[i];
      bf16_t* orow = y + (size_t)(rowb + i) * DINNER + h * 64;
#pragma unroll
      for (int ni = 0; ni < 4; ni++) {
        const int p = ni * 16 + l16;
        const float v = acc2[mi][ni][r] + df * bits2f(CtX[p * 136 + i]);
        orow[p] = __float2bfloat16(v);
      }
    }
  }
}

// ---- gated rmsnorm: yn = rmsnorm(y*silu(z))*w, bf16 in/out ----
__global__ __launch_bounds__(256) void k_gatenorm(const bf16_t* __restrict__ y,
                                                  const bf16_t* __restrict__ z,
                                                  const float* __restrict__ nw,
                                                  bf16_t* __restrict__ outp) {
  const int row = blockIdx.x, tid = threadIdx.x;
  const bf16_t* yr = y + (size_t)row * DINNER;
  const bf16_t* zr = z + (size_t)row * DINNER;
  float vals[16];
  float ss = 0.f;
#pragma unroll
  for (int k = 0; k < 16; k++) {
    int j = tid + k * 256;
    float v = bf2f(yr[j]) * siluf(bf2f(zr[j]));
    vals[k] = v; ss += v * v;
  }
  __shared__ float sbuf[4];
  for (int o = 32; o > 0; o >>= 1) ss += __shfl_down(ss, o, 64);
  if ((tid & 63) == 0) sbuf[tid >> 6] = ss;
  __syncthreads();
  float rinv = rsqrtf((sbuf[0] + sbuf[1] + sbuf[2] + sbuf[3]) / DINNER + EPSF);
  bf16_t* orow = outp + (size_t)row * DINNER;
#pragma unroll
  for (int k = 0; k < 16; k++) {
    int j = tid + k * 256;
    orow[j] = __float2bfloat16(vals[k] * rinv * nw[j]);
  }
}

__global__ void k_diag(float* out, float mb) { out[0] = mb; }

// ---- workspace layout (bytes), total ~245 MB ----
static constexpr size_t OFF_WBUF = 0;                                   // bf16 shared weight buf
static constexpr size_t SZ_WBUF  = (size_t)NPROJ * DMODEL * 2;
static constexpr size_t OFF_Z    = OFF_WBUF + SZ_WBUF;                  // bf16 [TOK][DINNER]
static constexpr size_t SZ_Z     = (size_t)TOK * DINNER * 2;
static constexpr size_t OFF_XBC  = OFF_Z + SZ_Z;                        // bf16 [TOK][CONVDIM]; later hbuf fp32
static constexpr size_t SZ_XBC   = (size_t)TOK * CONVDIM * 2;
static constexpr size_t OFF_DT   = OFF_XBC + SZ_XBC;
static constexpr size_t SZ_DT    = (size_t)TOK * NH * 4;
static constexpr size_t OFF_DAC  = OFF_DT + SZ_DT;
static constexpr size_t SZ_DAC   = (size_t)TOK * NH * 4;
static constexpr size_t OFF_CDEC = OFF_DAC + SZ_DAC;
static constexpr size_t SZ_CDEC  = (size_t)2 * 64 * NCHUNK * 4;
static constexpr size_t OFF_G    = OFF_CDEC + ((SZ_CDEC + 4095) & ~(size_t)4095);  // prevs; later h2n
static constexpr size_t SZ_G     = (size_t)2 * NCHUNK * 64 * 4096 * 4;
static constexpr size_t OFF_H    = OFF_G + SZ_G;                        // xBCraw; later yn; later act
static constexpr size_t SZ_H     = (size_t)TOK * CONVDIM * 2;
static constexpr size_t OFF_I    = OFF_H + SZ_H;                        // xn1; later states; later y
static constexpr size_t SZ_I     = (size_t)2 * NCHUNK * 64 * 4096 * 4;
static constexpr size_t WS_NEED  = OFF_I + SZ_I;

extern "C" void kernel_launch(void* const* d_in, const int* in_sizes, int n_in,
                              void* d_out, int out_size, void* d_ws, size_t ws_size,
                              hipStream_t stream) {
  (void)in_sizes; (void)n_in; (void)out_size;
  if (ws_size < WS_NEED) {
    k_diag<<<1, 1, 0, stream>>>((float*)d_out, (float)(ws_size / 1048576.0));
    return;
  }

  const float* hidden     = (const float*)d_in[0];
  const float* in_proj_w  = (const float*)d_in[1];
  const float* conv_w     = (const float*)d_in[2];
  const float* conv_b     = (const float*)d_in[3];
  const float* dt_bias    = (const float*)d_in[4];
  const float* A_log      = (const float*)d_in[5];
  const float* Dv         = (const float*)d_in[6];
  const float* norm_w     = (const float*)d_in[7];
  const float* out_proj_w = (const float*)d_in[8];
  const float* ln1_w      = (const float*)d_in[9];
  const float* ln2_w      = (const float*)d_in[10];
  const float* gate_w     = (const float*)d_in[11];
  const float* up_w       = (const float*)d_in[12];
  const float* down_w     = (const float*)d_in[13];

  char* ws = (char*)d_ws;
  bf16_t* Wbuf  = (bf16_t*)(ws + OFF_WBUF);
  bf16_t* z     = (bf16_t*)(ws + OFF_Z);
  bf16_t* xBC   = (bf16_t*)(ws + OFF_XBC);
  float*  hbuf  = (float*)(ws + OFF_XBC);   // overlay (xBC dead after yout)
  float*  dtb   = (float*)(ws + OFF_DT);
  float*  dAc   = (float*)(ws + OFF_DAC);
  float*  cdec  = (float*)(ws + OFF_CDEC);
  float*  prevs = (float*)(ws + OFF_G);
  bf16_t* h2n   = (bf16_t*)(ws + OFF_G);    // overlay (prevs dead after yout)
  bf16_t* xbcr  = (bf16_t*)(ws + OFF_H);
  bf16_t* yn    = (bf16_t*)(ws + OFF_H);    // overlay (xbcr dead after conv)
  bf16_t* act   = (bf16_t*)(ws + OFF_H);    // overlay (yn dead after out_proj)
  bf16_t* xn1   = (bf16_t*)(ws + OFF_I);
  float*  states= (float*)(ws + OFF_I);     // overlay (xn1 dead after in_proj)
  bf16_t* y     = (bf16_t*)(ws + OFF_I);    // overlay (states dead after scan)

  dim3 tb(32, 8);

  // ---- mamba block ----
  k_tcvt<<<dim3(NPROJ / 32, DMODEL / 32), tb, 0, stream>>>(in_proj_w, Wbuf, DMODEL, NPROJ, DIP, 0, 0);
  k_rmsnorm_bf16<<<TOK, 256, 0, stream>>>(hidden, ln1_w, xn1, DMODEL);
  k_gemm256<<<dim3(NPROJ / 256, TOK / 256), 512, 0, stream>>>(xn1, Wbuf, nullptr, z, xbcr, TOK, NPROJ, DMODEL, 3);
  k_conv<<<TOK, 256, 0, stream>>>(xbcr, conv_w, conv_b, xBC);
  k_dt<<<TOK, 256, 0, stream>>>(hidden, ln1_w, in_proj_w, dt_bias, dtb);
  k_dacum<<<128, 128, 0, stream>>>(dtb, A_log, dAc, cdec);
  k_states<<<2048, 256, 0, stream>>>(xBC, dtb, dAc, states);
  k_scan<<<2048, 256, 0, stream>>>(states, cdec, prevs);
  k_yout<<<2048, 256, 0, stream>>>(xBC, dtb, dAc, prevs, Dv, y);
  k_gatenorm<<<TOK, 256, 0, stream>>>(y, z, norm_w, yn);
  k_tcvt<<<dim3(DMODEL / 32, DINNER / 32), tb, 0, stream>>>(out_proj_w, Wbuf, DINNER, DMODEL, DMODEL, 0, 0);
  k_gemm<<<dim3(DMODEL / 128, TOK / 128), 256, 0, stream>>>(yn, Wbuf, hidden, hbuf, nullptr, TOK, DMODEL, DINNER, 0);

  // ---- MLP block (two N-halves to bound scratch) ----
  k_rmsnorm_bf16<<<TOK, 256, 0, stream>>>(hbuf, ln2_w, h2n, DMODEL);
  for (int g = 0; g < 2; g++) {
    const int HF = DFF / 2;  // 4096
    k_tcvt<<<dim3(HF / 32, DMODEL / 32), tb, 0, stream>>>(gate_w, Wbuf, DMODEL, HF, DFF, 0, g * HF);
    k_gemm256<<<dim3(HF / 256, TOK / 256), 512, 0, stream>>>(h2n, Wbuf, nullptr, act, nullptr, TOK, HF, DMODEL, 1);
    k_tcvt<<<dim3(HF / 32, DMODEL / 32), tb, 0, stream>>>(up_w, Wbuf, DMODEL, HF, DFF, 0, g * HF);
    k_gemm256<<<dim3(HF / 256, TOK / 256), 512, 0, stream>>>(h2n, Wbuf, nullptr, act, nullptr, TOK, HF, DMODEL, 2);
    k_tcvt<<<dim3(DMODEL / 32, HF / 32), tb, 0, stream>>>(down_w, Wbuf, HF, DMODEL, DMODEL, g * HF, 0);
    k_gemm<<<dim3(DMODEL / 128, TOK / 128), 256, 0, stream>>>(act, Wbuf, g == 0 ? hbuf : (float*)d_out,
                                                              d_out, nullptr, TOK, DMODEL, HF, 0);
  }
}